// Round 3
// baseline (4500.690 us; speedup 1.0000x reference)
//
#include <hip/hip_runtime.h>

#define H      51
#define T_IN   512
#define T_TOT  576
#define PITCH  52
// float offsets within smem
#define OFF_W1 0                          // Whh1: 204 x 52
#define OFF_W3 (204 * PITCH)              // Wih3 gates f,g,o: 153 x 52
#define OFF_P  (OFF_W3 + 153 * PITCH)     // partial buf: [2 elem][4 wave][52] float4
#define LDSFL  (OFF_P + 2 * 4 * PITCH * 4)// 20,228 floats = 80,912 B (2 blocks/CU)

__device__ __forceinline__ float bf2f(unsigned short u) {
    return __uint_as_float(((unsigned int)u) << 16);
}
__device__ __forceinline__ unsigned short f2bf(float f) {
    unsigned int u = __float_as_uint(f);
    u += 0x7fffu + ((u >> 16) & 1u);
    return (unsigned short)(u >> 16);
}
__device__ __forceinline__ float wget(const void* p, int i, bool is16) {
    return is16 ? bf2f(((const unsigned short*)p)[i]) : ((const float*)p)[i];
}
__device__ __forceinline__ float rl(float v, int k) {
    return __uint_as_float((unsigned int)__builtin_amdgcn_readlane((int)__float_as_uint(v), k));
}
__device__ __forceinline__ float sigm(float x) {
    x = fminf(fmaxf(x, -30.f), 30.f);
    return 1.f / (1.f + __expf(-x));
}
__device__ __forceinline__ float tanh_f(float x) {
    x = fminf(fmaxf(x, -15.f), 15.f);
    float e = __expf(2.f * x);
    return (e - 1.f) / (e + 1.f);
}
__device__ __forceinline__ float f4e(float4 v, int i) {
    return i == 0 ? v.x : i == 1 ? v.y : i == 2 ? v.z : v.w;
}

#define L13(M) M(0) M(1) M(2) M(3) M(4) M(5) M(6) M(7) M(8) M(9) M(10) M(11) M(12)

#define RED(sv) { sv += __shfl_xor(sv, 32, 64); sv += __shfl_xor(sv, 16, 64); \
    sv += __shfl_xor(sv, 8, 64); sv += __shfl_xor(sv, 4, 64); \
    sv += __shfl_xor(sv, 2, 64); sv += __shfl_xor(sv, 1, 64); }

// 512 blocks x 4 waves; block = 2 batch elements. Wave w owns k-slice 13w..13w+12
// of the register matrices (Wih2, Whh2, Whh3, Wih3-gate-i) and an aligned k-slice
// of the LDS matrices (Whh1, Wih3 f/g/o).
//
// Round-3 restructure (latency-chain): (a) UPD is REDUNDANT in all 4 waves for
// both elems -> h stays per-lane in registers, the hbuf round-trip (3x ~120cy on
// the chain) is gone, and UPD sits in the same basic block as independent FMA
// work so the scheduler hides it. (b) Each layer is split into Whh@h_old
// (depends only on last step) and Wih@h_new; the Whh block of layer L+1 runs
// inside UPD-L's window, and Whh1@h1(t) runs inside UPD-3's window. Every
// barrier window now has FMA work for all waves.
// Single partial buffer; 6 barriers, each required:
//   b1/b3/b5 = RAW on partials of L1/L2/L3; b2/b4/b6 = WAR (reads of L(i)
//   partials complete before the next write to the shared buffer).
// Register budget kept at round-0 level: c-states now 6 (was 3), REDUPD is
// elem-sequential (<=4 transient float4), biases still folded via wave-3 init.
extern "C" __global__ void __launch_bounds__(256)
__attribute__((amdgpu_waves_per_eu(2, 2)))
lstm3_kernel(const void* g_in,  const void* g_Wih1, const void* g_Whh1,
             const void* g_bih1, const void* g_bhh1,
             const void* g_Wih2, const void* g_Whh2, const void* g_bih2, const void* g_bhh2,
             const void* g_Wih3, const void* g_Whh3, const void* g_bih3, const void* g_bhh3,
             const void* g_Wlin, const void* g_blin, void* g_out)
{
    extern __shared__ float smem[];

    const int tid  = threadIdx.x;
    const int lane = tid & 63;
    const int wid  = tid >> 6;
    const int eb   = blockIdx.x * 2;
    const int jeff = (lane < H) ? lane : (H - 1);

    // ---- dtype sniff (proven: resolves fp32 on this harness)
    bool is16 = true;
    {
        const unsigned short* p = (const unsigned short*)g_Wih1;
        for (int i = 0; i < 204; ++i) {
            float v = fabsf(bf2f(p[i]));
            if (!(v < 0.2f)) is16 = false;
        }
    }

    // ---- LDS staging
    for (int i = tid; i < 204 * PITCH; i += 256) {
        int r = i / PITCH, k = i - r * PITCH;
        smem[OFF_W1 + i] = (k < H) ? wget(g_Whh1, r * H + k, is16) : 0.f;
    }
    for (int i = tid; i < 153 * PITCH; i += 256) {
        int r = i / PITCH, k = i - r * PITCH;
        smem[OFF_W3 + i] = (k < H) ? wget(g_Wih3, (H + r) * H + k, is16) : 0.f;
    }
    __syncthreads();

    const int kbR = 13 * wid;                                   // register k-slice
    const int kbL = (wid == 0) ? 0 : (wid == 1) ? 12 : (wid == 2) ? 28 : 40;
    const int nbL = (wid == 1) ? 4 : 3;                         // float4 blocks in LDS slice

#define WC(srcp, row, kk) (((kbR + (kk)) < H) ? wget(srcp, (row) * H + kbR + (kk), is16) : 0.f)
#define DECL13(p) float p##_0,p##_1,p##_2,p##_3,p##_4,p##_5,p##_6,p##_7,p##_8,p##_9,p##_10,p##_11,p##_12;
#define LOAD13(p, srcp, row) \
    p##_0 = WC(srcp, row, 0);  p##_1 = WC(srcp, row, 1);  p##_2 = WC(srcp, row, 2); \
    p##_3 = WC(srcp, row, 3);  p##_4 = WC(srcp, row, 4);  p##_5 = WC(srcp, row, 5); \
    p##_6 = WC(srcp, row, 6);  p##_7 = WC(srcp, row, 7);  p##_8 = WC(srcp, row, 8); \
    p##_9 = WC(srcp, row, 9);  p##_10 = WC(srcp, row, 10); p##_11 = WC(srcp, row, 11); \
    p##_12 = WC(srcp, row, 12);

    DECL13(wih2g0) DECL13(wih2g1) DECL13(wih2g2) DECL13(wih2g3)
    DECL13(whh2g0) DECL13(whh2g1) DECL13(whh2g2) DECL13(whh2g3)
    DECL13(whh3g0) DECL13(whh3g1) DECL13(whh3g2) DECL13(whh3g3)
    DECL13(wih3i)
    LOAD13(wih2g0, g_Wih2, 0 * H + jeff) LOAD13(wih2g1, g_Wih2, 1 * H + jeff)
    LOAD13(wih2g2, g_Wih2, 2 * H + jeff) LOAD13(wih2g3, g_Wih2, 3 * H + jeff)
    LOAD13(whh2g0, g_Whh2, 0 * H + jeff) LOAD13(whh2g1, g_Whh2, 1 * H + jeff)
    LOAD13(whh2g2, g_Whh2, 2 * H + jeff) LOAD13(whh2g3, g_Whh2, 3 * H + jeff)
    LOAD13(whh3g0, g_Whh3, 0 * H + jeff) LOAD13(whh3g1, g_Whh3, 1 * H + jeff)
    LOAD13(whh3g2, g_Whh3, 2 * H + jeff) LOAD13(whh3g3, g_Whh3, 3 * H + jeff)
    LOAD13(wih3i,  g_Wih3, 0 * H + jeff)

    const float b1_0 = wget(g_bih1, 0*H+jeff, is16) + wget(g_bhh1, 0*H+jeff, is16);
    const float b1_1 = wget(g_bih1, 1*H+jeff, is16) + wget(g_bhh1, 1*H+jeff, is16);
    const float b1_2 = wget(g_bih1, 2*H+jeff, is16) + wget(g_bhh1, 2*H+jeff, is16);
    const float b1_3 = wget(g_bih1, 3*H+jeff, is16) + wget(g_bhh1, 3*H+jeff, is16);
    const float b2_0 = wget(g_bih2, 0*H+jeff, is16) + wget(g_bhh2, 0*H+jeff, is16);
    const float b2_1 = wget(g_bih2, 1*H+jeff, is16) + wget(g_bhh2, 1*H+jeff, is16);
    const float b2_2 = wget(g_bih2, 2*H+jeff, is16) + wget(g_bhh2, 2*H+jeff, is16);
    const float b2_3 = wget(g_bih2, 3*H+jeff, is16) + wget(g_bhh2, 3*H+jeff, is16);
    const float b3_0 = wget(g_bih3, 0*H+jeff, is16) + wget(g_bhh3, 0*H+jeff, is16);
    const float b3_1 = wget(g_bih3, 1*H+jeff, is16) + wget(g_bhh3, 1*H+jeff, is16);
    const float b3_2 = wget(g_bih3, 2*H+jeff, is16) + wget(g_bhh3, 2*H+jeff, is16);
    const float b3_3 = wget(g_bih3, 3*H+jeff, is16) + wget(g_bhh3, 3*H+jeff, is16);
    const float wi1_0 = wget(g_Wih1, 0*H+jeff, is16);
    const float wi1_1 = wget(g_Wih1, 1*H+jeff, is16);
    const float wi1_2 = wget(g_Wih1, 2*H+jeff, is16);
    const float wi1_3 = wget(g_Wih1, 3*H+jeff, is16);
    const float wlinr = (lane < H) ? wget(g_Wlin, lane, is16) : 0.f;
    const float blinr = wget(g_blin, 0, is16);

    const float4* A1g0 = (const float4*)(smem + OFF_W1 + (0*H + jeff) * PITCH + kbL);
    const float4* A1g1 = (const float4*)(smem + OFF_W1 + (1*H + jeff) * PITCH + kbL);
    const float4* A1g2 = (const float4*)(smem + OFF_W1 + (2*H + jeff) * PITCH + kbL);
    const float4* A1g3 = (const float4*)(smem + OFF_W1 + (3*H + jeff) * PITCH + kbL);
    const float4* A3f  = (const float4*)(smem + OFF_W3 + (      jeff) * PITCH + kbL);
    const float4* A3g  = (const float4*)(smem + OFF_W3 + (H   + jeff) * PITCH + kbL);
    const float4* A3o  = (const float4*)(smem + OFF_W3 + (2*H + jeff) * PITCH + kbL);
    float4* ebufP = (float4*)(smem + OFF_P);

    float h1_0=0.f,h1_1=0.f,h2_0=0.f,h2_1=0.f,h3_0=0.f,h3_1=0.f;
    float c1_0=0.f,c1_1=0.f,c2_0=0.f,c2_1=0.f,c3_0=0.f,c3_1=0.f;   // redundant, all waves
    float xf0=0.f,xf1=0.f;                                          // redundant, all waves
    float xn0=0.f,xn1=0.f;                                          // prefetched x (wave 3)

    const unsigned short* in16 = (const unsigned short*)g_in;
    const float*          in32 = (const float*)g_in;
    unsigned short* o16w0 = (unsigned short*)g_out + (size_t)(eb+0)*T_TOT;
    unsigned short* o16w1 = (unsigned short*)g_out + (size_t)(eb+1)*T_TOT;
    float* o32w0 = (float*)g_out + (size_t)(eb+0)*T_TOT;
    float* o32w1 = (float*)g_out + (size_t)(eb+1)*T_TOT;

    if (wid == 3) {   // prefetch x(0)
        if (is16) { xn0 = bf2f(in16[(size_t)(eb+0)*T_IN]); xn1 = bf2f(in16[(size_t)(eb+1)*T_IN]); }
        else      { xn0 = in32[(size_t)(eb+0)*T_IN];       xn1 = in32[(size_t)(eb+1)*T_IN]; }
    }

    // ---- per-k partial macros (A = Whh@h_old part, B = Wih@h_new part) ----
#define P2A(kk) { \
    float r0_ = rl(h2_0, kbR+(kk)), r1_ = rl(h2_1, kbR+(kk)); \
    a0_0=fmaf(whh2g0_##kk,r0_,a0_0); a0_1=fmaf(whh2g0_##kk,r1_,a0_1); \
    a1_0=fmaf(whh2g1_##kk,r0_,a1_0); a1_1=fmaf(whh2g1_##kk,r1_,a1_1); \
    a2_0=fmaf(whh2g2_##kk,r0_,a2_0); a2_1=fmaf(whh2g2_##kk,r1_,a2_1); \
    a3_0=fmaf(whh2g3_##kk,r0_,a3_0); a3_1=fmaf(whh2g3_##kk,r1_,a3_1); }

#define P2B(kk) { \
    float s0_ = rl(h1_0, kbR+(kk)), s1_ = rl(h1_1, kbR+(kk)); \
    a0_0=fmaf(wih2g0_##kk,s0_,a0_0); a0_1=fmaf(wih2g0_##kk,s1_,a0_1); \
    a1_0=fmaf(wih2g1_##kk,s0_,a1_0); a1_1=fmaf(wih2g1_##kk,s1_,a1_1); \
    a2_0=fmaf(wih2g2_##kk,s0_,a2_0); a2_1=fmaf(wih2g2_##kk,s1_,a2_1); \
    a3_0=fmaf(wih2g3_##kk,s0_,a3_0); a3_1=fmaf(wih2g3_##kk,s1_,a3_1); }

#define P3A(kk) { \
    float r0_ = rl(h3_0, kbR+(kk)), r1_ = rl(h3_1, kbR+(kk)); \
    a0_0=fmaf(whh3g0_##kk,r0_,a0_0); a0_1=fmaf(whh3g0_##kk,r1_,a0_1); \
    a1_0=fmaf(whh3g1_##kk,r0_,a1_0); a1_1=fmaf(whh3g1_##kk,r1_,a1_1); \
    a2_0=fmaf(whh3g2_##kk,r0_,a2_0); a2_1=fmaf(whh3g2_##kk,r1_,a2_1); \
    a3_0=fmaf(whh3g3_##kk,r0_,a3_0); a3_1=fmaf(whh3g3_##kk,r1_,a3_1); }

#define P3I(kk) { \
    float s0_ = rl(h2_0, kbR+(kk)), s1_ = rl(h2_1, kbR+(kk)); \
    a0_0=fmaf(wih3i_##kk,s0_,a0_0);  a0_1=fmaf(wih3i_##kk,s1_,a0_1); }

    // write my partial rows for both elems; one barrier
#define WRP() { \
    if (lane < H) { \
        ebufP[(0*4 + wid)*PITCH + lane] = make_float4(a0_0, a1_0, a2_0, a3_0); \
        ebufP[(1*4 + wid)*PITCH + lane] = make_float4(a0_1, a1_1, a2_1, a3_1); \
    } \
    __syncthreads(); }

    // redundant update, all waves, elem-sequential (caps transient float4s at 4)
#define REDUPD(cm0, cm1, hv0, hv1) { \
    float4 q_ = ebufP[0*PITCH + jeff]; \
    float4 t_ = ebufP[1*PITCH + jeff]; q_.x+=t_.x; q_.y+=t_.y; q_.z+=t_.z; q_.w+=t_.w; \
    t_ = ebufP[2*PITCH + jeff]; q_.x+=t_.x; q_.y+=t_.y; q_.z+=t_.z; q_.w+=t_.w; \
    t_ = ebufP[3*PITCH + jeff]; q_.x+=t_.x; q_.y+=t_.y; q_.z+=t_.z; q_.w+=t_.w; \
    float i0_ = sigm(q_.x), f0_ = sigm(q_.y), g0_ = tanh_f(q_.z), o0_ = sigm(q_.w); \
    cm0 = f0_ * cm0 + i0_ * g0_; \
    hv0 = o0_ * tanh_f(cm0); \
    q_ = ebufP[4*PITCH + jeff]; \
    t_ = ebufP[5*PITCH + jeff]; q_.x+=t_.x; q_.y+=t_.y; q_.z+=t_.z; q_.w+=t_.w; \
    t_ = ebufP[6*PITCH + jeff]; q_.x+=t_.x; q_.y+=t_.y; q_.z+=t_.z; q_.w+=t_.w; \
    t_ = ebufP[7*PITCH + jeff]; q_.x+=t_.x; q_.y+=t_.y; q_.z+=t_.z; q_.w+=t_.w; \
    float i1_ = sigm(q_.x), f1_ = sigm(q_.y), g1_ = tanh_f(q_.z), o1_ = sigm(q_.w); \
    cm1 = f1_ * cm1 + i1_ * g1_; \
    hv1 = o1_ * tanh_f(cm1); }

    // accumulators: persist across the loop bottom (phase 5 pre-computes
    // Whh1@h1(t) for the NEXT step). Zero for t=0 (h1_old = 0).
    float a0_0=0.f,a1_0=0.f,a2_0=0.f,a3_0=0.f,a0_1=0.f,a1_1=0.f,a2_1=0.f,a3_1=0.f;

#pragma clang loop unroll(disable)
    for (int t = 0; t < T_TOT; ++t) {
        // ---- phase 0: acc already holds Whh1@h1_old; wave 3 adds x-term + b1
        if (wid == 3) {
            float x0 = (t < T_IN) ? xn0 : xf0;
            float x1 = (t < T_IN) ? xn1 : xf1;
            a0_0 += fmaf(wi1_0, x0, b1_0); a0_1 += fmaf(wi1_0, x1, b1_0);
            a1_0 += fmaf(wi1_1, x0, b1_1); a1_1 += fmaf(wi1_1, x1, b1_1);
            a2_0 += fmaf(wi1_2, x0, b1_2); a2_1 += fmaf(wi1_2, x1, b1_2);
            a3_0 += fmaf(wi1_3, x0, b1_3); a3_1 += fmaf(wi1_3, x1, b1_3);
        }
        WRP()                                   // b1

        // ---- phase 1: UPD1 (all waves, redundant) || Whh2@h2_old
        if (wid == 3 && t + 1 < T_IN) {         // prefetch x(t+1), consumed next phase 0
            if (is16) { xn0 = bf2f(in16[(size_t)(eb+0)*T_IN + t+1]); xn1 = bf2f(in16[(size_t)(eb+1)*T_IN + t+1]); }
            else      { xn0 = in32[(size_t)(eb+0)*T_IN + t+1];       xn1 = in32[(size_t)(eb+1)*T_IN + t+1]; }
        }
        if (wid == 3) {
            a0_0=a0_1=b2_0; a1_0=a1_1=b2_1; a2_0=a2_1=b2_2; a3_0=a3_1=b2_3;
        } else {
            a0_0=a1_0=a2_0=a3_0=a0_1=a1_1=a2_1=a3_1=0.f;
        }
        REDUPD(c1_0, c1_1, h1_0, h1_1)
        L13(P2A)
        __syncthreads();                        // b2 (WAR: partials-1 reads vs wr-2)

        // ---- phase 2: Wih2@h1(t)
        L13(P2B)
        WRP()                                   // b3

        // ---- phase 3: UPD2 || Whh3@h3_old
        if (wid == 3) {
            a0_0=a0_1=b3_0; a1_0=a1_1=b3_1; a2_0=a2_1=b3_2; a3_0=a3_1=b3_3;
        } else {
            a0_0=a1_0=a2_0=a3_0=a0_1=a1_1=a2_1=a3_1=0.f;
        }
        REDUPD(c2_0, c2_1, h2_0, h2_1)
        L13(P3A)
        __syncthreads();                        // b4 (WAR: partials-2 reads vs wr-3)

        // ---- phase 4: Wih3@h2(t): LDS gates f/g/o + register gate i
        for (int b = 0; b < nbL; ++b) {
            float4 uf = A3f[b], ug = A3g[b], uo = A3o[b];
#pragma unroll
            for (int i = 0; i < 4; ++i) {
                int k = kbL + 4*b + i;
                float s0 = rl(h2_0, k), s1 = rl(h2_1, k);
                a1_0 = fmaf(f4e(uf,i), s0, a1_0); a1_1 = fmaf(f4e(uf,i), s1, a1_1);
                a2_0 = fmaf(f4e(ug,i), s0, a2_0); a2_1 = fmaf(f4e(ug,i), s1, a2_1);
                a3_0 = fmaf(f4e(uo,i), s0, a3_0); a3_1 = fmaf(f4e(uo,i), s1, a3_1);
            }
        }
        L13(P3I)
        WRP()                                   // b5

        // ---- phase 5: UPD3 || Whh1@h1(t) (next step's layer-1 recurrent part)
        a0_0=a1_0=a2_0=a3_0=a0_1=a1_1=a2_1=a3_1=0.f;
        REDUPD(c3_0, c3_1, h3_0, h3_1)
        for (int b = 0; b < nbL; ++b) {
            float4 u0 = A1g0[b], u1 = A1g1[b], u2 = A1g2[b], u3 = A1g3[b];
#pragma unroll
            for (int i = 0; i < 4; ++i) {
                int k = kbL + 4*b + i;
                float s0 = rl(h1_0, k), s1 = rl(h1_1, k);
                a0_0 = fmaf(f4e(u0,i), s0, a0_0); a0_1 = fmaf(f4e(u0,i), s1, a0_1);
                a1_0 = fmaf(f4e(u1,i), s0, a1_0); a1_1 = fmaf(f4e(u1,i), s1, a1_1);
                a2_0 = fmaf(f4e(u2,i), s0, a2_0); a2_1 = fmaf(f4e(u2,i), s1, a2_1);
                a3_0 = fmaf(f4e(u3,i), s0, a3_0); a3_1 = fmaf(f4e(u3,i), s1, a3_1);
            }
        }
        // head: redundant in all waves (h3 is in-register)
        float s0 = wlinr * h3_0; RED(s0) float ov0 = s0 + blinr;
        float s1 = wlinr * h3_1; RED(s1) float ov1 = s1 + blinr;
        xf0 = ov0; xf1 = ov1;
        if (wid == 3 && lane == 0) {
            if (is16) { o16w0[t] = f2bf(ov0); o16w1[t] = f2bf(ov1); }
            else      { o32w0[t] = ov0;       o32w1[t] = ov1; }
        }
        __syncthreads();                        // b6 (WAR: partials-3 reads vs wr-1 next)
    }
}

extern "C" void kernel_launch(void* const* d_in, const int* in_sizes, int n_in,
                              void* d_out, int out_size, void* d_ws, size_t ws_size,
                              hipStream_t stream) {
    (void)in_sizes; (void)n_in; (void)d_ws; (void)ws_size; (void)out_size;
    size_t shmem = LDSFL * sizeof(float);   // 80,912 B -> 2 blocks/CU
    hipFuncSetAttribute((const void*)lstm3_kernel,
                        hipFuncAttributeMaxDynamicSharedMemorySize, (int)shmem);
    lstm3_kernel<<<dim3(512), dim3(256), shmem, stream>>>(
        d_in[0],  d_in[1],  d_in[2],  d_in[3],  d_in[4],
        d_in[5],  d_in[6],  d_in[7],  d_in[8],
        d_in[9],  d_in[10], d_in[11], d_in[12],
        d_in[13], d_in[14], d_out);
}

// Round 4
// 3651.557 us; speedup vs baseline: 1.2325x; 1.2325x over previous
//
#include <hip/hip_runtime.h>

#define H      51
#define T_IN   512
#define T_TOT  576
#define PITCH  52
// Bumped row layout: row r of a weight region starts at r*PITCH + (r>>3)*4.
// This makes the strided per-lane ds_read_b128 of A-tiles conflict-free
// (plain PITCH=52 gives 8-way conflicts: lanes j,j+8 differ by 416B = 0 mod 128).
#define ROFF(r) ((r) * PITCH + ((r) >> 3) * 4)
// float offsets within smem
#define OFF_W1 0                           // Whh1: 204 rows bumped = 10,708 floats
#define SZ_W1  (ROFF(203) + PITCH)
#define OFF_W3 (OFF_W1 + SZ_W1)            // Wih3 gates f,g,o: 153 rows bumped = 8,032
#define SZ_W3  (ROFF(152) + PITCH)
#define OFF_P  (OFF_W3 + SZ_W3)            // partial buf: [2 elem][4 wave][52] float4
#define LDSFL  (OFF_P + 2 * 4 * PITCH * 4) // 20,404 floats = 81,616 B (2 blocks/CU)

__device__ __forceinline__ float bf2f(unsigned short u) {
    return __uint_as_float(((unsigned int)u) << 16);
}
__device__ __forceinline__ unsigned short f2bf(float f) {
    unsigned int u = __float_as_uint(f);
    u += 0x7fffu + ((u >> 16) & 1u);
    return (unsigned short)(u >> 16);
}
__device__ __forceinline__ float wget(const void* p, int i, bool is16) {
    return is16 ? bf2f(((const unsigned short*)p)[i]) : ((const float*)p)[i];
}
__device__ __forceinline__ float rl(float v, int k) {
    return __uint_as_float((unsigned int)__builtin_amdgcn_readlane((int)__float_as_uint(v), k));
}
__device__ __forceinline__ float sigm(float x) {
    x = fminf(fmaxf(x, -30.f), 30.f);
    return 1.f / (1.f + __expf(-x));
}
__device__ __forceinline__ float tanh_f(float x) {
    x = fminf(fmaxf(x, -15.f), 15.f);
    float e = __expf(2.f * x);
    return (e - 1.f) / (e + 1.f);
}
__device__ __forceinline__ float f4e(float4 v, int i) {
    return i == 0 ? v.x : i == 1 ? v.y : i == 2 ? v.z : v.w;
}

#define L13(M) M(0) M(1) M(2) M(3) M(4) M(5) M(6) M(7) M(8) M(9) M(10) M(11) M(12)

#define RED(sv) { sv += __shfl_xor(sv, 32, 64); sv += __shfl_xor(sv, 16, 64); \
    sv += __shfl_xor(sv, 8, 64); sv += __shfl_xor(sv, 4, 64); \
    sv += __shfl_xor(sv, 2, 64); sv += __shfl_xor(sv, 1, 64); }

// 512 blocks x 4 waves; block = 2 batch elements. Wave w owns k-slice 13w..13w+12
// of the register matrices (Wih2, Whh2, Whh3, Wih3-gate-i: 169 regs/lane) and an
// aligned k-slice of the LDS matrices (Whh1, Wih3 f/g/o).
//
// Round-4: round-0 phase structure EXACTLY (acc dead during UPD windows; no
// persistent acc across loop bottom; biases/x folded via wave-3 acc init) --
// rounds 1/3 proved any extra persistent/transient pressure spills to scratch
// (WRITE_SIZE 3.8MB -> 25-68MB). Two surgical deltas, +3 persistent regs total:
//  (a) bumped LDS row layout (ROFF) -> A-tile ds_read_b128 conflict-free
//      (was 8-way, 7.6e7 conflict-cycles/dispatch);
//  (b) UPD is redundant in all 4 waves for both elems -> h stays in registers,
//      the hbuf write+barrier+read round-trip (~130cy x3/step on the serial
//      chain) is gone and no wave idles through the UPD window.
// Single partial buffer, 6 barriers: b1/b3/b5 RAW on partials, b2/b4/b6 WAR
// (partial reads of layer i complete before layer i+1's writes).
extern "C" __global__ void __launch_bounds__(256)
__attribute__((amdgpu_waves_per_eu(2, 2)))
lstm3_kernel(const void* g_in,  const void* g_Wih1, const void* g_Whh1,
             const void* g_bih1, const void* g_bhh1,
             const void* g_Wih2, const void* g_Whh2, const void* g_bih2, const void* g_bhh2,
             const void* g_Wih3, const void* g_Whh3, const void* g_bih3, const void* g_bhh3,
             const void* g_Wlin, const void* g_blin, void* g_out)
{
    extern __shared__ float smem[];

    const int tid  = threadIdx.x;
    const int lane = tid & 63;
    const int wid  = tid >> 6;
    const int eb   = blockIdx.x * 2;
    const int jeff = (lane < H) ? lane : (H - 1);

    // ---- dtype sniff
    bool is16 = true;
    {
        const unsigned short* p = (const unsigned short*)g_Wih1;
        for (int i = 0; i < 204; ++i) {
            float v = fabsf(bf2f(p[i]));
            if (!(v < 0.2f)) is16 = false;
        }
    }

    // ---- LDS staging (bumped row layout)
    for (int i = tid; i < 204 * PITCH; i += 256) {
        int r = i / PITCH, k = i - r * PITCH;
        smem[OFF_W1 + ROFF(r) + k] = (k < H) ? wget(g_Whh1, r * H + k, is16) : 0.f;
    }
    for (int i = tid; i < 153 * PITCH; i += 256) {
        int r = i / PITCH, k = i - r * PITCH;
        smem[OFF_W3 + ROFF(r) + k] = (k < H) ? wget(g_Wih3, (H + r) * H + k, is16) : 0.f;
    }
    __syncthreads();

    const int kbR = 13 * wid;                                   // register k-slice
    const int kbL = (wid == 0) ? 0 : (wid == 1) ? 12 : (wid == 2) ? 28 : 40;
    const int nbL = (wid == 1) ? 4 : 3;                         // float4 blocks in LDS slice

#define WC(srcp, row, kk) (((kbR + (kk)) < H) ? wget(srcp, (row) * H + kbR + (kk), is16) : 0.f)
#define DECL13(p) float p##_0,p##_1,p##_2,p##_3,p##_4,p##_5,p##_6,p##_7,p##_8,p##_9,p##_10,p##_11,p##_12;
#define LOAD13(p, srcp, row) \
    p##_0 = WC(srcp, row, 0);  p##_1 = WC(srcp, row, 1);  p##_2 = WC(srcp, row, 2); \
    p##_3 = WC(srcp, row, 3);  p##_4 = WC(srcp, row, 4);  p##_5 = WC(srcp, row, 5); \
    p##_6 = WC(srcp, row, 6);  p##_7 = WC(srcp, row, 7);  p##_8 = WC(srcp, row, 8); \
    p##_9 = WC(srcp, row, 9);  p##_10 = WC(srcp, row, 10); p##_11 = WC(srcp, row, 11); \
    p##_12 = WC(srcp, row, 12);

    DECL13(wih2g0) DECL13(wih2g1) DECL13(wih2g2) DECL13(wih2g3)
    DECL13(whh2g0) DECL13(whh2g1) DECL13(whh2g2) DECL13(whh2g3)
    DECL13(whh3g0) DECL13(whh3g1) DECL13(whh3g2) DECL13(whh3g3)
    DECL13(wih3i)
    LOAD13(wih2g0, g_Wih2, 0 * H + jeff) LOAD13(wih2g1, g_Wih2, 1 * H + jeff)
    LOAD13(wih2g2, g_Wih2, 2 * H + jeff) LOAD13(wih2g3, g_Wih2, 3 * H + jeff)
    LOAD13(whh2g0, g_Whh2, 0 * H + jeff) LOAD13(whh2g1, g_Whh2, 1 * H + jeff)
    LOAD13(whh2g2, g_Whh2, 2 * H + jeff) LOAD13(whh2g3, g_Whh2, 3 * H + jeff)
    LOAD13(whh3g0, g_Whh3, 0 * H + jeff) LOAD13(whh3g1, g_Whh3, 1 * H + jeff)
    LOAD13(whh3g2, g_Whh3, 2 * H + jeff) LOAD13(whh3g3, g_Whh3, 3 * H + jeff)
    LOAD13(wih3i,  g_Wih3, 0 * H + jeff)

    const float b1_0 = wget(g_bih1, 0*H+jeff, is16) + wget(g_bhh1, 0*H+jeff, is16);
    const float b1_1 = wget(g_bih1, 1*H+jeff, is16) + wget(g_bhh1, 1*H+jeff, is16);
    const float b1_2 = wget(g_bih1, 2*H+jeff, is16) + wget(g_bhh1, 2*H+jeff, is16);
    const float b1_3 = wget(g_bih1, 3*H+jeff, is16) + wget(g_bhh1, 3*H+jeff, is16);
    const float b2_0 = wget(g_bih2, 0*H+jeff, is16) + wget(g_bhh2, 0*H+jeff, is16);
    const float b2_1 = wget(g_bih2, 1*H+jeff, is16) + wget(g_bhh2, 1*H+jeff, is16);
    const float b2_2 = wget(g_bih2, 2*H+jeff, is16) + wget(g_bhh2, 2*H+jeff, is16);
    const float b2_3 = wget(g_bih2, 3*H+jeff, is16) + wget(g_bhh2, 3*H+jeff, is16);
    const float b3_0 = wget(g_bih3, 0*H+jeff, is16) + wget(g_bhh3, 0*H+jeff, is16);
    const float b3_1 = wget(g_bih3, 1*H+jeff, is16) + wget(g_bhh3, 1*H+jeff, is16);
    const float b3_2 = wget(g_bih3, 2*H+jeff, is16) + wget(g_bhh3, 2*H+jeff, is16);
    const float b3_3 = wget(g_bih3, 3*H+jeff, is16) + wget(g_bhh3, 3*H+jeff, is16);
    const float wi1_0 = wget(g_Wih1, 0*H+jeff, is16);
    const float wi1_1 = wget(g_Wih1, 1*H+jeff, is16);
    const float wi1_2 = wget(g_Wih1, 2*H+jeff, is16);
    const float wi1_3 = wget(g_Wih1, 3*H+jeff, is16);
    const float wlinr = (lane < H) ? wget(g_Wlin, lane, is16) : 0.f;
    const float blinr = wget(g_blin, 0, is16);

    // A-tile pointers: bumped row base + k-slice (all multiples of 4 floats)
    const float4* A1g0 = (const float4*)(smem + OFF_W1 + ROFF(0*H + jeff) + kbL);
    const float4* A1g1 = (const float4*)(smem + OFF_W1 + ROFF(1*H + jeff) + kbL);
    const float4* A1g2 = (const float4*)(smem + OFF_W1 + ROFF(2*H + jeff) + kbL);
    const float4* A1g3 = (const float4*)(smem + OFF_W1 + ROFF(3*H + jeff) + kbL);
    const float4* A3f  = (const float4*)(smem + OFF_W3 + ROFF(      jeff) + kbL);
    const float4* A3g  = (const float4*)(smem + OFF_W3 + ROFF(H   + jeff) + kbL);
    const float4* A3o  = (const float4*)(smem + OFF_W3 + ROFF(2*H + jeff) + kbL);
    float4* ebufP = (float4*)(smem + OFF_P);

    float h1_0=0.f,h1_1=0.f,h2_0=0.f,h2_1=0.f,h3_0=0.f,h3_1=0.f;
    float c1_0=0.f,c1_1=0.f,c2_0=0.f,c2_1=0.f,c3_0=0.f,c3_1=0.f;   // redundant, all waves
    float xf0=0.f,xf1=0.f;                                          // wave 3 only

    const unsigned short* in16 = (const unsigned short*)g_in;
    const float*          in32 = (const float*)g_in;
    unsigned short* o16w0 = (unsigned short*)g_out + (size_t)(eb+0)*T_TOT;
    unsigned short* o16w1 = (unsigned short*)g_out + (size_t)(eb+1)*T_TOT;
    float* o32w0 = (float*)g_out + (size_t)(eb+0)*T_TOT;
    float* o32w1 = (float*)g_out + (size_t)(eb+1)*T_TOT;

#define P2(kk) { \
    float s0_ = rl(h1_0, kbR+(kk)), s1_ = rl(h1_1, kbR+(kk)); \
    float r0_ = rl(h2_0, kbR+(kk)), r1_ = rl(h2_1, kbR+(kk)); \
    a0_0=fmaf(wih2g0_##kk,s0_,a0_0); a0_1=fmaf(wih2g0_##kk,s1_,a0_1); \
    a1_0=fmaf(wih2g1_##kk,s0_,a1_0); a1_1=fmaf(wih2g1_##kk,s1_,a1_1); \
    a2_0=fmaf(wih2g2_##kk,s0_,a2_0); a2_1=fmaf(wih2g2_##kk,s1_,a2_1); \
    a3_0=fmaf(wih2g3_##kk,s0_,a3_0); a3_1=fmaf(wih2g3_##kk,s1_,a3_1); \
    a0_0=fmaf(whh2g0_##kk,r0_,a0_0); a0_1=fmaf(whh2g0_##kk,r1_,a0_1); \
    a1_0=fmaf(whh2g1_##kk,r0_,a1_0); a1_1=fmaf(whh2g1_##kk,r1_,a1_1); \
    a2_0=fmaf(whh2g2_##kk,r0_,a2_0); a2_1=fmaf(whh2g2_##kk,r1_,a2_1); \
    a3_0=fmaf(whh2g3_##kk,r0_,a3_0); a3_1=fmaf(whh2g3_##kk,r1_,a3_1); }

#define P3(kk) { \
    float s0_ = rl(h2_0, kbR+(kk)), s1_ = rl(h2_1, kbR+(kk)); \
    float r0_ = rl(h3_0, kbR+(kk)), r1_ = rl(h3_1, kbR+(kk)); \
    a0_0=fmaf(wih3i_##kk,s0_,a0_0);  a0_1=fmaf(wih3i_##kk,s1_,a0_1); \
    a0_0=fmaf(whh3g0_##kk,r0_,a0_0); a0_1=fmaf(whh3g0_##kk,r1_,a0_1); \
    a1_0=fmaf(whh3g1_##kk,r0_,a1_0); a1_1=fmaf(whh3g1_##kk,r1_,a1_1); \
    a2_0=fmaf(whh3g2_##kk,r0_,a2_0); a2_1=fmaf(whh3g2_##kk,r1_,a2_1); \
    a3_0=fmaf(whh3g3_##kk,r0_,a3_0); a3_1=fmaf(whh3g3_##kk,r1_,a3_1); }

    // write my partial rows for both elems; barrier (RAW)
#define WRP() { \
    if (lane < H) { \
        ebufP[(0*4 + wid)*PITCH + lane] = make_float4(a0_0, a1_0, a2_0, a3_0); \
        ebufP[(1*4 + wid)*PITCH + lane] = make_float4(a0_1, a1_1, a2_1, a3_1); \
    } \
    __syncthreads(); }

    // redundant update, all waves, elem-sequential (caps transient float4s at 4);
    // accumulators a* are DEAD here (just written to LDS) -- keeps peak pressure
    // at round-0 level. Followed by a WAR barrier at the call site.
#define REDUPD(cm0, cm1, hv0, hv1) { \
    float4 q_ = ebufP[0*PITCH + jeff]; \
    float4 t_ = ebufP[1*PITCH + jeff]; q_.x+=t_.x; q_.y+=t_.y; q_.z+=t_.z; q_.w+=t_.w; \
    t_ = ebufP[2*PITCH + jeff]; q_.x+=t_.x; q_.y+=t_.y; q_.z+=t_.z; q_.w+=t_.w; \
    t_ = ebufP[3*PITCH + jeff]; q_.x+=t_.x; q_.y+=t_.y; q_.z+=t_.z; q_.w+=t_.w; \
    float i0_ = sigm(q_.x), f0_ = sigm(q_.y), g0_ = tanh_f(q_.z), o0_ = sigm(q_.w); \
    cm0 = f0_ * cm0 + i0_ * g0_; \
    hv0 = o0_ * tanh_f(cm0); \
    q_ = ebufP[4*PITCH + jeff]; \
    t_ = ebufP[5*PITCH + jeff]; q_.x+=t_.x; q_.y+=t_.y; q_.z+=t_.z; q_.w+=t_.w; \
    t_ = ebufP[6*PITCH + jeff]; q_.x+=t_.x; q_.y+=t_.y; q_.z+=t_.z; q_.w+=t_.w; \
    t_ = ebufP[7*PITCH + jeff]; q_.x+=t_.x; q_.y+=t_.y; q_.z+=t_.z; q_.w+=t_.w; \
    float i1_ = sigm(q_.x), f1_ = sigm(q_.y), g1_ = tanh_f(q_.z), o1_ = sigm(q_.w); \
    cm1 = f1_ * cm1 + i1_ * g1_; \
    hv1 = o1_ * tanh_f(cm1); \
    __syncthreads(); }

#pragma clang loop unroll(disable)
    for (int t = 0; t < T_TOT; ++t) {
        float a0_0,a1_0,a2_0,a3_0,a0_1,a1_1,a2_1,a3_1;

        // ---------------- layer 1 ----------------
        if (wid == 3) {
            float x0, x1;
            if (t < T_IN) {
                if (is16) {
                    x0 = bf2f(in16[(size_t)(eb+0)*T_IN + t]);
                    x1 = bf2f(in16[(size_t)(eb+1)*T_IN + t]);
                } else {
                    x0 = in32[(size_t)(eb+0)*T_IN + t];
                    x1 = in32[(size_t)(eb+1)*T_IN + t];
                }
            } else { x0 = xf0; x1 = xf1; }
            a0_0 = fmaf(wi1_0, x0, b1_0); a0_1 = fmaf(wi1_0, x1, b1_0);
            a1_0 = fmaf(wi1_1, x0, b1_1); a1_1 = fmaf(wi1_1, x1, b1_1);
            a2_0 = fmaf(wi1_2, x0, b1_2); a2_1 = fmaf(wi1_2, x1, b1_2);
            a3_0 = fmaf(wi1_3, x0, b1_3); a3_1 = fmaf(wi1_3, x1, b1_3);
        } else {
            a0_0=a1_0=a2_0=a3_0=a0_1=a1_1=a2_1=a3_1=0.f;
        }
        for (int b = 0; b < nbL; ++b) {
            float4 u0 = A1g0[b], u1 = A1g1[b], u2 = A1g2[b], u3 = A1g3[b];
#pragma unroll
            for (int i = 0; i < 4; ++i) {
                int k = kbL + 4*b + i;
                float s0 = rl(h1_0, k), s1 = rl(h1_1, k);
                a0_0 = fmaf(f4e(u0,i), s0, a0_0); a0_1 = fmaf(f4e(u0,i), s1, a0_1);
                a1_0 = fmaf(f4e(u1,i), s0, a1_0); a1_1 = fmaf(f4e(u1,i), s1, a1_1);
                a2_0 = fmaf(f4e(u2,i), s0, a2_0); a2_1 = fmaf(f4e(u2,i), s1, a2_1);
                a3_0 = fmaf(f4e(u3,i), s0, a3_0); a3_1 = fmaf(f4e(u3,i), s1, a3_1);
            }
        }
        WRP()                                 // b1 (RAW)
        REDUPD(c1_0, c1_1, h1_0, h1_1)        // + b2 (WAR)

        // ---------------- layer 2 ----------------
        if (wid == 3) {
            a0_0=a0_1=b2_0; a1_0=a1_1=b2_1; a2_0=a2_1=b2_2; a3_0=a3_1=b2_3;
        } else {
            a0_0=a1_0=a2_0=a3_0=a0_1=a1_1=a2_1=a3_1=0.f;
        }
        L13(P2)
        WRP()                                 // b3 (RAW)
        REDUPD(c2_0, c2_1, h2_0, h2_1)        // + b4 (WAR)

        // ---------------- layer 3 ----------------
        if (wid == 3) {
            a0_0=a0_1=b3_0; a1_0=a1_1=b3_1; a2_0=a2_1=b3_2; a3_0=a3_1=b3_3;
        } else {
            a0_0=a1_0=a2_0=a3_0=a0_1=a1_1=a2_1=a3_1=0.f;
        }
        for (int b = 0; b < nbL; ++b) {
            float4 uf = A3f[b], ug = A3g[b], uo = A3o[b];
#pragma unroll
            for (int i = 0; i < 4; ++i) {
                int k = kbL + 4*b + i;
                float s0 = rl(h2_0, k), s1 = rl(h2_1, k);
                a1_0 = fmaf(f4e(uf,i), s0, a1_0); a1_1 = fmaf(f4e(uf,i), s1, a1_1);
                a2_0 = fmaf(f4e(ug,i), s0, a2_0); a2_1 = fmaf(f4e(ug,i), s1, a2_1);
                a3_0 = fmaf(f4e(uo,i), s0, a3_0); a3_1 = fmaf(f4e(uo,i), s1, a3_1);
            }
        }
        L13(P3)
        WRP()                                 // b5 (RAW)
        REDUPD(c3_0, c3_1, h3_0, h3_1)        // + b6 (WAR)

        // ---------------- head: wave 3 only (h3 is in-register) ----------------
        if (wid == 3) {
            float s0 = wlinr * h3_0; RED(s0) float ov0 = s0 + blinr;
            float s1 = wlinr * h3_1; RED(s1) float ov1 = s1 + blinr;
            xf0 = ov0; xf1 = ov1;
            if (lane == 0) {
                if (is16) { o16w0[t] = f2bf(ov0); o16w1[t] = f2bf(ov1); }
                else      { o32w0[t] = ov0;       o32w1[t] = ov1; }
            }
        }
    }
}

extern "C" void kernel_launch(void* const* d_in, const int* in_sizes, int n_in,
                              void* d_out, int out_size, void* d_ws, size_t ws_size,
                              hipStream_t stream) {
    (void)in_sizes; (void)n_in; (void)d_ws; (void)ws_size; (void)out_size;
    size_t shmem = LDSFL * sizeof(float);   // 81,616 B -> 2 blocks/CU
    hipFuncSetAttribute((const void*)lstm3_kernel,
                        hipFuncAttributeMaxDynamicSharedMemorySize, (int)shmem);
    lstm3_kernel<<<dim3(512), dim3(256), shmem, stream>>>(
        d_in[0],  d_in[1],  d_in[2],  d_in[3],  d_in[4],
        d_in[5],  d_in[6],  d_in[7],  d_in[8],
        d_in[9],  d_in[10], d_in[11], d_in[12],
        d_in[13], d_in[14], d_out);
}

// Round 5
// 3056.654 us; speedup vs baseline: 1.4724x; 1.1946x over previous
//
#include <hip/hip_runtime.h>

#define H      51
#define T_IN   512
#define T_TOT  576
#define PITCH  52
// float offsets within smem.
// Gate-PAIRED LDS layouts so packed v_pk_fma_f32 can consume weight pairs:
//   W1P : Whh1, [pair p][row j][k*2+g]  (p=0 -> gates i,f ; p=1 -> gates g,o), 104 floats/row
//   W3GO: Wih3 gates (g,o) paired,      [row j][k*2+g], 104 floats/row
//   W3F : Wih3 gate f alone,            [row j][52]
// Total LDS byte-identical to the proven round-0 kernel: 81,328 B -> 2 blocks/CU.
#define OFF_W1   0
#define SZ_W1    (2 * 51 * 104)           // 10,608
#define OFF_W3GO (OFF_W1 + SZ_W1)         // 10,608
#define SZ_W3GO  (51 * 104)               //  5,304
#define OFF_W3F  (OFF_W3GO + SZ_W3GO)     // 15,912
#define SZ_W3F   (51 * 52)                //  2,652
#define OFF_P    (OFF_W3F + SZ_W3F)       // 18,564 : partials [2 elem][4 wave][52] float4
#define OFF_H    (OFF_P + 2 * 4 * PITCH * 4) // 20,228 : h broadcast [2 elem][52]
#define LDSFL    (OFF_H + 2 * PITCH)      // 20,332 floats = 81,328 B

typedef float v2f __attribute__((ext_vector_type(2)));

__device__ __forceinline__ float bf2f(unsigned short u) {
    return __uint_as_float(((unsigned int)u) << 16);
}
__device__ __forceinline__ unsigned short f2bf(float f) {
    unsigned int u = __float_as_uint(f);
    u += 0x7fffu + ((u >> 16) & 1u);
    return (unsigned short)(u >> 16);
}
__device__ __forceinline__ float wget(const void* p, int i, bool is16) {
    return is16 ? bf2f(((const unsigned short*)p)[i]) : ((const float*)p)[i];
}
__device__ __forceinline__ float rl(float v, int k) {
    return __uint_as_float((unsigned int)__builtin_amdgcn_readlane((int)__float_as_uint(v), k));
}
__device__ __forceinline__ float sigm(float x) {
    x = fminf(fmaxf(x, -30.f), 30.f);
    return 1.f / (1.f + __expf(-x));
}
__device__ __forceinline__ float tanh_f(float x) {
    x = fminf(fmaxf(x, -15.f), 15.f);
    float e = __expf(2.f * x);
    return (e - 1.f) / (e + 1.f);
}
__device__ __forceinline__ float f4e(float4 v, int i) {
    return i == 0 ? v.x : i == 1 ? v.y : i == 2 ? v.z : v.w;
}
// packed fma: a += w * splat(s)  -> v_pk_fma_f32 (2 FMAs / instruction)
__device__ __forceinline__ v2f fma2(v2f w, float s, v2f a) {
#if __has_builtin(__builtin_elementwise_fma)
    return __builtin_elementwise_fma(w, (v2f){s, s}, a);
#else
    v2f r; r.x = fmaf(w.x, s, a.x); r.y = fmaf(w.y, s, a.y); return r;
#endif
}
#define V2(a, b) ((v2f){(a), (b)})

#define L13(M) M(0) M(1) M(2) M(3) M(4) M(5) M(6) M(7) M(8) M(9) M(10) M(11) M(12)

#define RED(sv) { sv += __shfl_xor(sv, 32, 64); sv += __shfl_xor(sv, 16, 64); \
    sv += __shfl_xor(sv, 8, 64); sv += __shfl_xor(sv, 4, 64); \
    sv += __shfl_xor(sv, 2, 64); sv += __shfl_xor(sv, 1, 64); }

// 512 blocks x 4 waves; block = 2 batch elements. Wave w owns k-slice 13w..13w+12
// of the register matrices and an aligned k-slice of the LDS matrices.
// Round-5: IDENTICAL structure/barriers/exchange to the proven round-0 kernel
// (best: 3061us). Single change: all matmul FMAs are gate-paired into packed
// v_pk_fma_f32 (accumulator pairs P0=(i,f), P1=(g,o); weight pairs persistent
// v2f registers; LDS regions re-interleaved pairwise at identical total size).
// Register budget unchanged: 78 v2f + 13 scalar = 169 weight floats/lane.
// Rounds 1/3/4 proved: any extra persistent/transient pressure spills
// (WRITE_SIZE canary) and any LDS re-stride backfires -- so neither is touched.
extern "C" __global__ void __launch_bounds__(256)
__attribute__((amdgpu_waves_per_eu(2, 2)))
lstm3_kernel(const void* g_in,  const void* g_Wih1, const void* g_Whh1,
             const void* g_bih1, const void* g_bhh1,
             const void* g_Wih2, const void* g_Whh2, const void* g_bih2, const void* g_bhh2,
             const void* g_Wih3, const void* g_Whh3, const void* g_bih3, const void* g_bhh3,
             const void* g_Wlin, const void* g_blin, void* g_out)
{
    extern __shared__ float smem[];

    const int tid  = threadIdx.x;
    const int lane = tid & 63;
    const int wid  = tid >> 6;
    const int eb   = blockIdx.x * 2;
    const int jeff = (lane < H) ? lane : (H - 1);

    // ---- dtype sniff (proven: resolves fp32 on this harness)
    bool is16 = true;
    {
        const unsigned short* p = (const unsigned short*)g_Wih1;
        for (int i = 0; i < 204; ++i) {
            float v = fabsf(bf2f(p[i]));
            if (!(v < 0.2f)) is16 = false;
        }
    }

    // ---- LDS staging (gate-paired layouts)
    for (int i = tid; i < 2 * 51 * 104; i += 256) {          // Whh1 pairs
        int p = i / (51 * 104); int r = i - p * 51 * 104;
        int j = r / 104; int c = r - j * 104;
        int k = c >> 1, g = c & 1;
        smem[OFF_W1 + i] = (k < H) ? wget(g_Whh1, ((2 * p + g) * H + j) * H + k, is16) : 0.f;
    }
    for (int i = tid; i < 51 * 104; i += 256) {              // Wih3 gates (g,o)
        int j = i / 104; int c = i - j * 104;
        int k = c >> 1, g = c & 1;
        smem[OFF_W3GO + i] = (k < H) ? wget(g_Wih3, ((2 + g) * H + j) * H + k, is16) : 0.f;
    }
    for (int i = tid; i < 51 * 52; i += 256) {               // Wih3 gate f
        int j = i / 52; int k = i - j * 52;
        smem[OFF_W3F + i] = (k < H) ? wget(g_Wih3, (1 * H + j) * H + k, is16) : 0.f;
    }
    __syncthreads();

    const int kbR = 13 * wid;                                   // register k-slice
    const int kbL = (wid == 0) ? 0 : (wid == 1) ? 12 : (wid == 2) ? 28 : 40;
    const int nbL = (wid == 1) ? 4 : 3;                         // 4-k blocks in LDS slice
    const int nbP = (wid == 1) ? 8 : 6;                         // 2-k (b128) blocks, paired

#define WC(srcp, row, kk) (((kbR + (kk)) < H) ? wget(srcp, (row) * H + kbR + (kk), is16) : 0.f)
#define DECL13(p) float p##_0,p##_1,p##_2,p##_3,p##_4,p##_5,p##_6,p##_7,p##_8,p##_9,p##_10,p##_11,p##_12;
#define DECL13V(p) v2f p##_0,p##_1,p##_2,p##_3,p##_4,p##_5,p##_6,p##_7,p##_8,p##_9,p##_10,p##_11,p##_12;
#define LOAD13(p, srcp, row) \
    p##_0 = WC(srcp, row, 0);  p##_1 = WC(srcp, row, 1);  p##_2 = WC(srcp, row, 2); \
    p##_3 = WC(srcp, row, 3);  p##_4 = WC(srcp, row, 4);  p##_5 = WC(srcp, row, 5); \
    p##_6 = WC(srcp, row, 6);  p##_7 = WC(srcp, row, 7);  p##_8 = WC(srcp, row, 8); \
    p##_9 = WC(srcp, row, 9);  p##_10 = WC(srcp, row, 10); p##_11 = WC(srcp, row, 11); \
    p##_12 = WC(srcp, row, 12);
#define LOAD13V(p, srcp, rA, rB) \
    p##_0  = V2(WC(srcp, rA, 0),  WC(srcp, rB, 0));  p##_1  = V2(WC(srcp, rA, 1),  WC(srcp, rB, 1)); \
    p##_2  = V2(WC(srcp, rA, 2),  WC(srcp, rB, 2));  p##_3  = V2(WC(srcp, rA, 3),  WC(srcp, rB, 3)); \
    p##_4  = V2(WC(srcp, rA, 4),  WC(srcp, rB, 4));  p##_5  = V2(WC(srcp, rA, 5),  WC(srcp, rB, 5)); \
    p##_6  = V2(WC(srcp, rA, 6),  WC(srcp, rB, 6));  p##_7  = V2(WC(srcp, rA, 7),  WC(srcp, rB, 7)); \
    p##_8  = V2(WC(srcp, rA, 8),  WC(srcp, rB, 8));  p##_9  = V2(WC(srcp, rA, 9),  WC(srcp, rB, 9)); \
    p##_10 = V2(WC(srcp, rA, 10), WC(srcp, rB, 10)); p##_11 = V2(WC(srcp, rA, 11), WC(srcp, rB, 11)); \
    p##_12 = V2(WC(srcp, rA, 12), WC(srcp, rB, 12));

    DECL13V(wih2p0) DECL13V(wih2p1)
    DECL13V(whh2p0) DECL13V(whh2p1)
    DECL13V(whh3p0) DECL13V(whh3p1)
    DECL13(wih3i)
    LOAD13V(wih2p0, g_Wih2, 0 * H + jeff, 1 * H + jeff)
    LOAD13V(wih2p1, g_Wih2, 2 * H + jeff, 3 * H + jeff)
    LOAD13V(whh2p0, g_Whh2, 0 * H + jeff, 1 * H + jeff)
    LOAD13V(whh2p1, g_Whh2, 2 * H + jeff, 3 * H + jeff)
    LOAD13V(whh3p0, g_Whh3, 0 * H + jeff, 1 * H + jeff)
    LOAD13V(whh3p1, g_Whh3, 2 * H + jeff, 3 * H + jeff)
    LOAD13(wih3i,  g_Wih3, 0 * H + jeff)

    const v2f b1p0 = V2(wget(g_bih1, 0*H+jeff, is16) + wget(g_bhh1, 0*H+jeff, is16),
                        wget(g_bih1, 1*H+jeff, is16) + wget(g_bhh1, 1*H+jeff, is16));
    const v2f b1p1 = V2(wget(g_bih1, 2*H+jeff, is16) + wget(g_bhh1, 2*H+jeff, is16),
                        wget(g_bih1, 3*H+jeff, is16) + wget(g_bhh1, 3*H+jeff, is16));
    const v2f b2p0 = V2(wget(g_bih2, 0*H+jeff, is16) + wget(g_bhh2, 0*H+jeff, is16),
                        wget(g_bih2, 1*H+jeff, is16) + wget(g_bhh2, 1*H+jeff, is16));
    const v2f b2p1 = V2(wget(g_bih2, 2*H+jeff, is16) + wget(g_bhh2, 2*H+jeff, is16),
                        wget(g_bih2, 3*H+jeff, is16) + wget(g_bhh2, 3*H+jeff, is16));
    const v2f b3p0 = V2(wget(g_bih3, 0*H+jeff, is16) + wget(g_bhh3, 0*H+jeff, is16),
                        wget(g_bih3, 1*H+jeff, is16) + wget(g_bhh3, 1*H+jeff, is16));
    const v2f b3p1 = V2(wget(g_bih3, 2*H+jeff, is16) + wget(g_bhh3, 2*H+jeff, is16),
                        wget(g_bih3, 3*H+jeff, is16) + wget(g_bhh3, 3*H+jeff, is16));
    const v2f wi1p0 = V2(wget(g_Wih1, 0*H+jeff, is16), wget(g_Wih1, 1*H+jeff, is16));
    const v2f wi1p1 = V2(wget(g_Wih1, 2*H+jeff, is16), wget(g_Wih1, 3*H+jeff, is16));
    const float wlinr = (lane < H) ? wget(g_Wlin, lane, is16) : 0.f;
    const float blinr = wget(g_blin, 0, is16);

    // per-lane LDS base pointers (all float4-aligned)
    const float4* A1p0 = (const float4*)(smem + OFF_W1 + 0 * 51 * 104 + jeff * 104 + kbL * 2);
    const float4* A1p1 = (const float4*)(smem + OFF_W1 + 1 * 51 * 104 + jeff * 104 + kbL * 2);
    const float4* A3go = (const float4*)(smem + OFF_W3GO + jeff * 104 + kbL * 2);
    const float4* A3f  = (const float4*)(smem + OFF_W3F  + jeff * 52  + kbL);
    float4* ebufP = (float4*)(smem + OFF_P);
    float*  hbuf  = smem + OFF_H;

    float h1_0=0.f,h1_1=0.f,h2_0=0.f,h2_1=0.f,h3_0=0.f,h3_1=0.f;
    float c1my=0.f,c2my=0.f,c3my=0.f;      // live in waves 0/2 only
    float xf0=0.f,xf1=0.f;                 // wave 3 only

    const unsigned short* in16 = (const unsigned short*)g_in;
    const float*          in32 = (const float*)g_in;
    unsigned short* o16w0 = (unsigned short*)g_out + (size_t)(eb+0)*T_TOT;
    unsigned short* o16w1 = (unsigned short*)g_out + (size_t)(eb+1)*T_TOT;
    float* o32w0 = (float*)g_out + (size_t)(eb+0)*T_TOT;
    float* o32w1 = (float*)g_out + (size_t)(eb+1)*T_TOT;

#define P2(kk) { \
    float s0_ = rl(h1_0, kbR+(kk)), s1_ = rl(h1_1, kbR+(kk)); \
    float r0_ = rl(h2_0, kbR+(kk)), r1_ = rl(h2_1, kbR+(kk)); \
    aP0_0 = fma2(wih2p0_##kk, s0_, aP0_0); aP0_1 = fma2(wih2p0_##kk, s1_, aP0_1); \
    aP1_0 = fma2(wih2p1_##kk, s0_, aP1_0); aP1_1 = fma2(wih2p1_##kk, s1_, aP1_1); \
    aP0_0 = fma2(whh2p0_##kk, r0_, aP0_0); aP0_1 = fma2(whh2p0_##kk, r1_, aP0_1); \
    aP1_0 = fma2(whh2p1_##kk, r0_, aP1_0); aP1_1 = fma2(whh2p1_##kk, r1_, aP1_1); }

#define P3(kk) { \
    float s0_ = rl(h2_0, kbR+(kk)), s1_ = rl(h2_1, kbR+(kk)); \
    float r0_ = rl(h3_0, kbR+(kk)), r1_ = rl(h3_1, kbR+(kk)); \
    aP0_0.x = fmaf(wih3i_##kk, s0_, aP0_0.x);  aP0_1.x = fmaf(wih3i_##kk, s1_, aP0_1.x); \
    aP0_0 = fma2(whh3p0_##kk, r0_, aP0_0); aP0_1 = fma2(whh3p0_##kk, r1_, aP0_1); \
    aP1_0 = fma2(whh3p1_##kk, r0_, aP1_0); aP1_1 = fma2(whh3p1_##kk, r1_, aP1_1); }

    // exchange partials; waves 0/2 reduce+UPD for elem 0/1; h rebroadcast via LDS
    // (identical to round-0; gate order (i,f,g,o) = (P0.x,P0.y,P1.x,P1.y))
#define EXCHL(hv0, hv1, cmy) { \
    if (lane < H) { \
        ebufP[(0*4 + wid)*PITCH + lane] = make_float4(aP0_0.x, aP0_0.y, aP1_0.x, aP1_0.y); \
        ebufP[(1*4 + wid)*PITCH + lane] = make_float4(aP0_1.x, aP0_1.y, aP1_1.x, aP1_1.y); \
    } \
    __syncthreads(); \
    if ((wid & 1) == 0) { \
        const float4* pb_ = ebufP + (wid >> 1) * 4 * PITCH; \
        float4 q_ = pb_[0*PITCH + jeff]; \
        float4 t_ = pb_[1*PITCH + jeff]; q_.x+=t_.x; q_.y+=t_.y; q_.z+=t_.z; q_.w+=t_.w; \
        t_ = pb_[2*PITCH + jeff]; q_.x+=t_.x; q_.y+=t_.y; q_.z+=t_.z; q_.w+=t_.w; \
        t_ = pb_[3*PITCH + jeff]; q_.x+=t_.x; q_.y+=t_.y; q_.z+=t_.z; q_.w+=t_.w; \
        float ig_ = sigm(q_.x), fg_ = sigm(q_.y), gg_ = tanh_f(q_.z), og_ = sigm(q_.w); \
        cmy = fg_ * cmy + ig_ * gg_; \
        float hn_ = og_ * tanh_f(cmy); \
        if (lane < H) hbuf[(wid >> 1) * PITCH + lane] = hn_; \
    } \
    __syncthreads(); \
    hv0 = hbuf[0*PITCH + jeff]; \
    hv1 = hbuf[1*PITCH + jeff]; }

#pragma clang loop unroll(disable)
    for (int t = 0; t < T_TOT; ++t) {
        v2f aP0_0, aP1_0, aP0_1, aP1_1;

        // ---------------- layer 1 ----------------
        if (wid == 3) {
            float x0, x1;
            if (t < T_IN) {
                if (is16) {
                    x0 = bf2f(in16[(size_t)(eb+0)*T_IN + t]);
                    x1 = bf2f(in16[(size_t)(eb+1)*T_IN + t]);
                } else {
                    x0 = in32[(size_t)(eb+0)*T_IN + t];
                    x1 = in32[(size_t)(eb+1)*T_IN + t];
                }
            } else { x0 = xf0; x1 = xf1; }
            aP0_0 = fma2(wi1p0, x0, b1p0); aP0_1 = fma2(wi1p0, x1, b1p0);
            aP1_0 = fma2(wi1p1, x0, b1p1); aP1_1 = fma2(wi1p1, x1, b1p1);
        } else {
            aP0_0 = aP1_0 = aP0_1 = aP1_1 = (v2f){0.f, 0.f};
        }
        for (int b = 0; b < nbP; ++b) {
            float4 u0 = A1p0[b], u1 = A1p1[b];        // pair (i,f) / (g,o), 2 k each
            int k0 = kbL + 2*b;
            float s00 = rl(h1_0, k0),   s01 = rl(h1_1, k0);
            float s10 = rl(h1_0, k0+1), s11 = rl(h1_1, k0+1);
            v2f wA = V2(u0.x, u0.y), wB = V2(u0.z, u0.w);
            v2f wC = V2(u1.x, u1.y), wD = V2(u1.z, u1.w);
            aP0_0 = fma2(wA, s00, aP0_0); aP0_1 = fma2(wA, s01, aP0_1);
            aP0_0 = fma2(wB, s10, aP0_0); aP0_1 = fma2(wB, s11, aP0_1);
            aP1_0 = fma2(wC, s00, aP1_0); aP1_1 = fma2(wC, s01, aP1_1);
            aP1_0 = fma2(wD, s10, aP1_0); aP1_1 = fma2(wD, s11, aP1_1);
        }
        EXCHL(h1_0, h1_1, c1my)

        // ---------------- layer 2 ----------------
        if (wid == 3) {
            aP0_0 = b2p0; aP0_1 = b2p0; aP1_0 = b2p1; aP1_1 = b2p1;
        } else {
            aP0_0 = aP1_0 = aP0_1 = aP1_1 = (v2f){0.f, 0.f};
        }
        L13(P2)
        EXCHL(h2_0, h2_1, c2my)

        // ---------------- layer 3 ----------------
        if (wid == 3) {
            aP0_0 = b3p0; aP0_1 = b3p0; aP1_0 = b3p1; aP1_1 = b3p1;
        } else {
            aP0_0 = aP1_0 = aP0_1 = aP1_1 = (v2f){0.f, 0.f};
        }
        for (int b = 0; b < nbL; ++b) {
            float4 uf  = A3f[b];                      // 4 k of gate f
            float4 ug0 = A3go[2*b], ug1 = A3go[2*b+1]; // pairs (g,o), 2 k each
#pragma unroll
            for (int i = 0; i < 4; ++i) {
                int k = kbL + 4*b + i;
                float s0 = rl(h2_0, k), s1 = rl(h2_1, k);
                float wf = f4e(uf, i);
                v2f wgo = (i == 0) ? V2(ug0.x, ug0.y) : (i == 1) ? V2(ug0.z, ug0.w)
                         : (i == 2) ? V2(ug1.x, ug1.y) : V2(ug1.z, ug1.w);
                aP0_0.y = fmaf(wf, s0, aP0_0.y); aP0_1.y = fmaf(wf, s1, aP0_1.y);
                aP1_0 = fma2(wgo, s0, aP1_0);    aP1_1 = fma2(wgo, s1, aP1_1);
            }
        }
        L13(P3)
        EXCHL(h3_0, h3_1, c3my)

        // ---------------- head: wave 3 only ----------------
        if (wid == 3) {
            float s0 = wlinr * h3_0; RED(s0) float ov0 = s0 + blinr;
            float s1 = wlinr * h3_1; RED(s1) float ov1 = s1 + blinr;
            xf0 = ov0; xf1 = ov1;
            if (lane == 0) {
                if (is16) { o16w0[t] = f2bf(ov0); o16w1[t] = f2bf(ov1); }
                else      { o32w0[t] = ov0;       o32w1[t] = ov1; }
            }
        }
    }
}

extern "C" void kernel_launch(void* const* d_in, const int* in_sizes, int n_in,
                              void* d_out, int out_size, void* d_ws, size_t ws_size,
                              hipStream_t stream) {
    (void)in_sizes; (void)n_in; (void)d_ws; (void)ws_size; (void)out_size;
    size_t shmem = LDSFL * sizeof(float);   // 81,328 B -> 2 blocks/CU
    hipFuncSetAttribute((const void*)lstm3_kernel,
                        hipFuncAttributeMaxDynamicSharedMemorySize, (int)shmem);
    lstm3_kernel<<<dim3(512), dim3(256), shmem, stream>>>(
        d_in[0],  d_in[1],  d_in[2],  d_in[3],  d_in[4],
        d_in[5],  d_in[6],  d_in[7],  d_in[8],
        d_in[9],  d_in[10], d_in[11], d_in[12],
        d_in[13], d_in[14], d_out);
}